// Round 11
// baseline (488.920 us; speedup 1.0000x reference)
//
#include <hip/hip_runtime.h>
#include <hip/hip_bf16.h>

#define N_NODES 50000
#define N_RELS 8
#define IN_DIM 128
#define OUT_DIM 128
#define N_EDGES 800000
#define NR (N_NODES * N_RELS)              /* 400000 keys (tgt*8+rel) */
#define KDIM (N_RELS * IN_DIM)             /* 1024 = GEMM K */
#define PRE_NB 782                         /* prelude blocks; capacity 1024 */
#define PRE_T 512
#define PRE_THREADS (PRE_NB * PRE_T)       /* 400384 >= NR */
#define SCB 391                            /* scan blocks: 391*1024 >= NR */
#define FUSE_BLKS 1563                     /* 1563 * 32 = 50016 >= N_NODES */

typedef __attribute__((ext_vector_type(8))) short bf16x8;
typedef __attribute__((ext_vector_type(4))) float floatx4;
typedef __attribute__((ext_vector_type(4))) unsigned int uintx4;

__device__ inline unsigned short f2bf(float f) {
    unsigned u = __builtin_bit_cast(unsigned, f);
    u += 0x7fff + ((u >> 16) & 1);   // round-to-nearest-even
    return (unsigned short)(u >> 16);
}
__device__ inline float bflo(unsigned u) {   // low bf16 of a packed pair
    return __builtin_bit_cast(float, u << 16);
}
__device__ inline float bfhi(unsigned u) {   // high bf16 of a packed pair
    return __builtin_bit_cast(float, u & 0xffff0000u);
}

// device-scope spin barrier (cg::grid_group::sync internals, capture-safe).
// Requires all PRE_NB blocks resident: 512 thr = 8 waves, launch_bounds
// (512,8) -> 4 blk/CU cap (VGPR<=64, LDS 2KB) -> 1024 >= 782. OK.
__device__ __forceinline__ void grid_bar(int* __restrict__ bar, int idx, int nblk) {
    __syncthreads();
    if (threadIdx.x == 0) {
        __threadfence();                               // release (wbL2)
        atomicAdd(&bar[idx], 1);
        while (__hip_atomic_load(&bar[idx], __ATOMIC_RELAXED,
                                 __HIP_MEMORY_SCOPE_AGENT) < nblk)
            __builtin_amdgcn_s_sleep(1);
        __threadfence();                               // acquire (invL1/L2)
    }
    __syncthreads();
}

// ================= prelude: prep + histogram + scan + scatter =================
// R19: r10's cooperative launch silently failed under graph capture (out was
// all zeros -> absmax == max|ref|). Same boundary-elimination theory, plain
// launch + spin barriers. P0 (Wtf/featB convert) || P1 (histogram) merged:
// cnt is pre-zeroed by the host memset, and P0's outputs are consumed only by
// the NEXT dispatch. 3 barriers replace 3 dispatch boundaries.
__global__ __launch_bounds__(512, 8) void prelude_kernel(
    const int* __restrict__ tri, const float* __restrict__ features,
    const float* __restrict__ W,
    unsigned short* __restrict__ Wtf, unsigned short* __restrict__ featB,
    int* __restrict__ cnt, int* __restrict__ bar,
    int* __restrict__ segOff, int* __restrict__ cursor,
    int* __restrict__ bsum, int* __restrict__ sortedSrc)
{
    __shared__ int s_int[512];
    const int tid = threadIdx.x;
    const int b = blockIdx.x;
    const int gid = b * PRE_T + tid;          // 0 .. 400383

    // ---------- P0 || P1 ----------
    if (gid < N_RELS * IN_DIM * OUT_DIM) {
        const int idx = gid;
        int e  = idx & 7;
        int l  = (idx >> 3) & 63;
        int ks = (idx >> 9) & 31;
        int nt = idx >> 14;
        int o = nt * 16 + (l & 15);
        int k = ks * 32 + (l >> 4) * 8 + e;             // global K index
        Wtf[idx] = f2bf(W[(k >> 7) * (IN_DIM * OUT_DIM) + (k & 127) * OUT_DIM + o]);
    }
    for (int t = gid; t < N_NODES * IN_DIM / 8; t += PRE_THREADS) {
        const float4* f4 = (const float4*)features;
        float4 x = f4[2 * t], y = f4[2 * t + 1];
        uint4 o;
        o.x = (unsigned)f2bf(x.x) | ((unsigned)f2bf(x.y) << 16);
        o.y = (unsigned)f2bf(x.z) | ((unsigned)f2bf(x.w) << 16);
        o.z = (unsigned)f2bf(y.x) | ((unsigned)f2bf(y.y) << 16);
        o.w = (unsigned)f2bf(y.z) | ((unsigned)f2bf(y.w) << 16);
        ((uint4*)featB)[t] = o;
    }
    if (gid < N_EDGES / 4) {                  // histogram, 4 edges via int4 x3
        const int4* tri4 = (const int4*)tri;
        int4 a = tri4[3 * gid], v = tri4[3 * gid + 1], c = tri4[3 * gid + 2];
        // edges: (a.x,a.y,a.z) (a.w,v.x,v.y) (v.z,v.w,c.x) (c.y,c.z,c.w)
        atomicAdd(&cnt[a.z * N_RELS + a.y], 1);
        atomicAdd(&cnt[v.y * N_RELS + v.x], 1);
        atomicAdd(&cnt[c.x * N_RELS + v.w], 1);
        atomicAdd(&cnt[c.w * N_RELS + c.z], 1);
    }
    grid_bar(bar, 0, PRE_NB);

    // ---------- P2a: per-block partial sums (chunk = 1024) ----------
    if (b < SCB) {
        const int base = b * 1024 + tid * 2;
        int v0 = (base     < NR) ? cnt[base]     : 0;
        int v1 = (base + 1 < NR) ? cnt[base + 1] : 0;
        s_int[tid] = v0 + v1;
        __syncthreads();
        for (int off = 256; off > 0; off >>= 1) {
            if (tid < off) s_int[tid] += s_int[tid + off];
            __syncthreads();
        }
        if (tid == 0) bsum[b] = s_int[0];
    }
    grid_bar(bar, 1, PRE_NB);

    // ---------- P2b: exclusive scan -> segOff, cursor ----------
    if (b < SCB) {
        // redundant in-LDS scan of the 391 block sums (no communication)
        int vb = (tid < SCB) ? bsum[tid] : 0;
        s_int[tid] = vb; __syncthreads();
        for (int off = 1; off < 512; off <<= 1) {
            int x = (tid >= off) ? s_int[tid - off] : 0;
            __syncthreads();
            s_int[tid] += x;
            __syncthreads();
        }
        const int boff = (b == 0) ? 0 : s_int[b - 1];
        __syncthreads();

        const int base = b * 1024 + tid * 2;
        int v0 = (base     < NR) ? cnt[base]     : 0;
        int v1 = (base + 1 < NR) ? cnt[base + 1] : 0;
        const int sum = v0 + v1;
        s_int[tid] = sum; __syncthreads();
        for (int off = 1; off < 512; off <<= 1) {
            int x = (tid >= off) ? s_int[tid - off] : 0;
            __syncthreads();
            s_int[tid] += x;
            __syncthreads();
        }
        int run = boff + s_int[tid] - sum;   // exclusive offset
        if (base < NR)     { segOff[base] = run;     cursor[base] = run;     run += v0; }
        if (base + 1 < NR) { segOff[base + 1] = run; cursor[base + 1] = run; }
        if (b == 0 && tid == 0) segOff[NR] = N_EDGES;
    }
    grid_bar(bar, 2, PRE_NB);

    // ---------- P3: scatter (4 edges/thread, 4 independent chains) ----------
    if (gid < N_EDGES / 4) {
        const int4* tri4 = (const int4*)tri;
        int4 a = tri4[3 * gid], v = tri4[3 * gid + 1], c = tri4[3 * gid + 2];
        int p0 = atomicAdd(&cursor[a.z * N_RELS + a.y], 1);
        int p1 = atomicAdd(&cursor[v.y * N_RELS + v.x], 1);
        int p2 = atomicAdd(&cursor[c.x * N_RELS + v.w], 1);
        int p3 = atomicAdd(&cursor[c.w * N_RELS + c.z], 1);
        sortedSrc[p0] = a.x;
        sortedSrc[p1] = a.w;
        sortedSrc[p2] = v.z;
        sortedSrc[p3] = c.y;
    }
}

// ---------------- fused agg + GEMM (byte-identical to verified r9) ----------
__global__ __launch_bounds__(512, 8) void fused_kernel(
    const int* __restrict__ sortedSrc, const int* __restrict__ segOff,
    const unsigned short* __restrict__ featB,
    const unsigned short* __restrict__ Wtf,
    const float* __restrict__ bias,
    float* __restrict__ out)
{
    __shared__ __align__(16) unsigned short Atile[32 * 512]; // 32 KB
    const int tid = threadIdx.x;
    const int wave = tid >> 6, lane = tid & 63;
    const int q = lane >> 4, l16 = lane & 15;    // quarter / lane-in-quarter
    const int m0 = blockIdx.x * 32;
    const int wm = wave & 1, wn = wave >> 1;     // 2 (M) x 4 (N) wave grid

    floatx4 acc[2];
#pragma unroll
    for (int nt = 0; nt < 2; ++nt) acc[nt] = (floatx4){0.f, 0.f, 0.f, 0.f};

    const unsigned short* fb = featB + 8 * l16;  // dims 8*l16 .. 8*l16+7

#pragma unroll
    for (int p = 0; p < 2; ++p) {
        // ---- agg phase: 4 nodes per wave, quarter q handles rel 4p+q ----
        for (int i = 0; i < 4; ++i) {
            const int nl = wave * 4 + i;         // local row 0..31
            const int node = m0 + nl;
            if (node < N_NODES) {
                int bnd = 0;
                if (lane < 5) bnd = segOff[node * N_RELS + 4 * p + lane];
                int sg[5];
#pragma unroll
                for (int k = 0; k < 5; ++k) sg[k] = __shfl(bnd, k);

                const int e0 = sg[0], eN = sg[4];
                int srcw = 0;
                if (e0 + lane < eN) srcw = sortedSrc[e0 + lane];  // 64-src window

                const int s0v = sg[q], s1v = sg[q + 1];
                const int len = s1v - s0v;
                int m0x = __shfl_xor(len, 16);               // full exec
                int jm = (len > m0x) ? len : m0x;
                int m1x = __shfl_xor(jm, 32);                // full exec
                const int jmax = (jm > m1x) ? jm : m1x;      // wave-uniform
                float a0 = 0.f, a1 = 0.f, a2 = 0.f, a3 = 0.f;
                float a4 = 0.f, a5 = 0.f, a6 = 0.f, a7 = 0.f;
                for (int j = 0; j < jmax; j += 2) {          // uniform trips
                    const int ea = s0v + j;
                    const int ia = ea - e0;
                    const int swina = __shfl(srcw, ia & 63); // full exec
                    const int ib = ia + 1;
                    const int swinb = __shfl(srcw, ib & 63); // full exec
                    const bool pa = j < len;
                    const bool pb = j + 1 < len;
                    int srca = 0, srcb = 0;
                    if (pa) srca = (ia < 64) ? swina : sortedSrc[ea];
                    if (pb) srcb = (ib < 64) ? swinb : sortedSrc[ea + 1];
                    uint4 ua = *(const uint4*)&fb[srca * IN_DIM];
                    uint4 ub = *(const uint4*)&fb[srcb * IN_DIM];
                    if (pa) {
                        a0 += bflo(ua.x); a1 += bfhi(ua.x);
                        a2 += bflo(ua.y); a3 += bfhi(ua.y);
                        a4 += bflo(ua.z); a5 += bfhi(ua.z);
                        a6 += bflo(ua.w); a7 += bfhi(ua.w);
                    }
                    if (pb) {
                        a0 += bflo(ub.x); a1 += bfhi(ub.x);
                        a2 += bflo(ub.y); a3 += bfhi(ub.y);
                        a4 += bflo(ub.z); a5 += bfhi(ub.z);
                        a6 += bflo(ub.w); a7 += bfhi(ub.w);
                    }
                }
                const float inv = (len > 0) ? 1.0f / (float)len : 0.0f;
                uintx4 pk;
                pk[0] = (unsigned)f2bf(a0 * inv) | ((unsigned)f2bf(a1 * inv) << 16);
                pk[1] = (unsigned)f2bf(a2 * inv) | ((unsigned)f2bf(a3 * inv) << 16);
                pk[2] = (unsigned)f2bf(a4 * inv) | ((unsigned)f2bf(a5 * inv) << 16);
                pk[3] = (unsigned)f2bf(a6 * inv) | ((unsigned)f2bf(a7 * inv) << 16);
                // unit u = q*16+l16 holds cols u*8..u*8+7; XOR-swizzle by row
                const int us = (q * 16 + l16) ^ (nl & 15);
                *(uintx4*)&Atile[(nl * 64 + us) * 8] = pk;
            }
        }
        __syncthreads();                 // A-tile chunk visible

        // ---- GEMM phase: K-chunk p (512 cols), wave-tile 16x32 ----
        __builtin_amdgcn_s_setprio(1);
#pragma unroll
        for (int ksl = 0; ksl < 16; ++ksl) {
            const int ks = p * 16 + ksl;             // global k-slice
            const int r = wm * 16 + l16;
            const int us = (ksl * 4 + q) ^ (r & 15);
            bf16x8 a = *(const bf16x8*)&Atile[(r * 64 + us) * 8];
#pragma unroll
            for (int nt = 0; nt < 2; ++nt) {
                const int ntg = wn * 2 + nt;
                bf16x8 b = *(const bf16x8*)&Wtf[(size_t)((ntg * 32 + ks) * 64 + lane) * 8];
                acc[nt] = __builtin_amdgcn_mfma_f32_16x16x32_bf16(a, b, acc[nt], 0, 0, 0);
            }
        }
        __builtin_amdgcn_s_setprio(0);
        __syncthreads();                 // reads done before next pass writes
    }

    // ---- epilogue: acc -> LDS (D-layout scatter) -> full-line NT stores ----
    float* fbuf = (float*)Atile;     // 32 rows x 128 f32 = 16 KB
#pragma unroll
    for (int nt = 0; nt < 2; ++nt) {
        const int o = (wn * 2 + nt) * 16 + l16;
        const float bv = bias[o];
#pragma unroll
        for (int j = 0; j < 4; ++j) {
            const int r = wm * 16 + q * 4 + j;   // local row 0..31
            fbuf[r * 128 + o] = acc[nt][j] + bv;
        }
    }
    __syncthreads();
    {
        const int row = tid >> 4;            // 0..31
        const int col = (tid & 15) * 8;      // 0..120
        const int node = m0 + row;
        if (node < N_NODES) {
            floatx4 w0 = *(const floatx4*)&fbuf[row * 128 + col];
            floatx4 w1 = *(const floatx4*)&fbuf[row * 128 + col + 4];
            float* po = &out[(size_t)node * OUT_DIM + col];
            __builtin_nontemporal_store(w0, (floatx4*)po);
            __builtin_nontemporal_store(w1, (floatx4*)(po + 4));
        }
    }
}

extern "C" void kernel_launch(void* const* d_in, const int* in_sizes, int n_in,
                              void* d_out, int out_size, void* d_ws, size_t ws_size,
                              hipStream_t stream)
{
    const int*   tri      = (const int*)d_in[0];
    const float* features = (const float*)d_in[1];
    const float* W        = (const float*)d_in[2];
    const float* bias     = (const float*)d_in[3];
    float* out = (float*)d_out;

    char* ws = (char*)d_ws;
    unsigned short* Wtf = (unsigned short*)ws; ws += (size_t)OUT_DIM * KDIM * 2;  // 256 KB
    int* cnt       = (int*)ws; ws += (size_t)NR * 4;
    int* bar       = (int*)ws; ws += 16 * 4;          // barrier counters
    int* segOff    = (int*)ws; ws += (size_t)(NR + 4) * 4;
    int* cursor    = (int*)ws; ws += (size_t)NR * 4;
    int* bsum      = (int*)ws; ws += (size_t)512 * 4;
    int* sortedSrc = (int*)ws; ws += (size_t)N_EDGES * 4;
    unsigned short* featB = (unsigned short*)ws; ws += (size_t)N_NODES * IN_DIM * 2;  // 12.8 MB
    (void)ws_size; (void)in_sizes; (void)n_in; (void)out_size;

    hipMemsetAsync(cnt, 0, (NR + 16) * sizeof(int), stream);   // cnt + bar
    prelude_kernel<<<PRE_NB, PRE_T, 0, stream>>>(
        tri, features, W, Wtf, featB, cnt, bar, segOff, cursor, bsum, sortedSrc);
    fused_kernel<<<FUSE_BLKS, PRE_T, 0, stream>>>(
        sortedSrc, segOff, featB, Wtf, bias, out);
}

// Round 12
// 284.614 us; speedup vs baseline: 1.7178x; 1.7178x over previous
//
#include <hip/hip_runtime.h>
#include <hip/hip_bf16.h>

#define N_NODES 50000
#define N_RELS 8
#define IN_DIM 128
#define OUT_DIM 128
#define N_EDGES 800000
#define KDIM (N_RELS * IN_DIM)             /* 1024 = GEMM K */
#define NBKT 1563                          /* buckets = tiles of 32 nodes */
#define CAP 2048                           /* entries/bucket; load ~Po(512) */
#define FUSE_BLKS NBKT
#define EG_BLKS ((N_EDGES / 4 + 255) / 256)    /* 782 edge-group blocks */
#define CW_BLKS ((N_RELS * IN_DIM * OUT_DIM + 255) / 256) /* 512 */
#define FB_BLKS ((N_NODES * IN_DIM / 8 + 255) / 256)      /* 3125 */

typedef __attribute__((ext_vector_type(8))) short bf16x8;
typedef __attribute__((ext_vector_type(4))) float floatx4;
typedef __attribute__((ext_vector_type(4))) unsigned int uintx4;

__device__ inline unsigned short f2bf(float f) {
    unsigned u = __builtin_bit_cast(unsigned, f);
    u += 0x7fff + ((u >> 16) & 1);   // round-to-nearest-even
    return (unsigned short)(u >> 16);
}
__device__ inline float bflo(unsigned u) {   // low bf16 of a packed pair
    return __builtin_bit_cast(float, u << 16);
}
__device__ inline float bfhi(unsigned u) {   // high bf16 of a packed pair
    return __builtin_bit_cast(float, u & 0xffff0000u);
}

// ---------------- prep2: bucket-append + W/feature conversion ----------------
// R20: r11 measured dispatch boundaries at ~24 us each (488.9 - 332.8 - 83.5
// over 3 boundaries); the 6-dispatch counting-sort chain carried ~130 us of
// boundary cost. Replace hist+scan+scan+scatter with ONE bucket-append pass:
// entry = src(16b) | rel(3b at 16) | tgt&31(5b at 19); bucket = tgt>>5.
// Buckets are per-fused-tile, CAP=2048 >> Po(512) tail. 6 -> 3 dispatches.
__global__ void prep2_kernel(const int* __restrict__ tri, const float* __restrict__ W,
                             const float* __restrict__ features,
                             int* __restrict__ bcnt, int* __restrict__ bdata,
                             unsigned short* __restrict__ Wtf,
                             unsigned short* __restrict__ featB) {
    const int b = blockIdx.x;
    if (b < EG_BLKS) {
        int t = b * 256 + threadIdx.x;
        if (t >= N_EDGES / 4) return;
        const int4* tri4 = (const int4*)tri;
        int4 a = tri4[3 * t], v = tri4[3 * t + 1], c = tri4[3 * t + 2];
        // edges: (a.x,a.y,a.z) (a.w,v.x,v.y) (v.z,v.w,c.x) (c.y,c.z,c.w)
        int s[4] = { a.x, a.w, v.z, c.y };
        int r[4] = { a.y, v.x, v.w, c.z };
        int g[4] = { a.z, v.y, c.x, c.w };
#pragma unroll
        for (int k = 0; k < 4; ++k) {
            const int bkt = g[k] >> 5;
            const int pos = atomicAdd(&bcnt[bkt], 1);
            bdata[bkt * CAP + pos] = s[k] | (r[k] << 16) | ((g[k] & 31) << 19);
        }
    } else if (b < EG_BLKS + CW_BLKS) {
        int idx = (b - EG_BLKS) * 256 + threadIdx.x;   // 0 .. 131071
        if (idx >= N_RELS * IN_DIM * OUT_DIM) return;
        int e  = idx & 7;
        int l  = (idx >> 3) & 63;
        int ks = (idx >> 9) & 31;
        int nt = idx >> 14;
        int o = nt * 16 + (l & 15);
        int k = ks * 32 + (l >> 4) * 8 + e;             // global K index
        Wtf[idx] = f2bf(W[(k >> 7) * (IN_DIM * OUT_DIM) + (k & 127) * OUT_DIM + o]);
    } else {
        int t = (b - EG_BLKS - CW_BLKS) * 256 + threadIdx.x;   // 8 floats each
        if (t >= N_NODES * IN_DIM / 8) return;
        const float4* f4 = (const float4*)features;
        float4 x = f4[2 * t], y = f4[2 * t + 1];
        uint4 o;
        o.x = (unsigned)f2bf(x.x) | ((unsigned)f2bf(x.y) << 16);
        o.y = (unsigned)f2bf(x.z) | ((unsigned)f2bf(x.w) << 16);
        o.z = (unsigned)f2bf(y.x) | ((unsigned)f2bf(y.y) << 16);
        o.w = (unsigned)f2bf(y.z) | ((unsigned)f2bf(y.w) << 16);
        ((uint4*)featB)[t] = o;
    }
}

// ---------------- fused: in-block LDS sort + agg + GEMM ----------------
// Sort: 256-key (node*8+rel) LDS hist -> Hillis-Steele scan -> LDS scatter
// into srcS (ushort). Then the verified r9 gather/GEMM/epilogue, with src
// read from LDS (quarter-uniform broadcast; no shfl window, loop divergence
// safe). LDS: 32KB Atile + 4KB srcS + 3KB tables -> 4 blocks/CU.
__global__ __launch_bounds__(512, 8) void fused_kernel(
    const int* __restrict__ bcnt, const int* __restrict__ bdata,
    const unsigned short* __restrict__ featB,
    const unsigned short* __restrict__ Wtf,
    const float* __restrict__ bias,
    float* __restrict__ out)
{
    __shared__ __align__(16) unsigned short Atile[32 * 512]; // 32 KB
    __shared__ unsigned short srcS[CAP];                     // 4 KB
    __shared__ int cntL[256];
    __shared__ int segL[256];
    __shared__ int curL[256];
    __shared__ int s_n;

    const int tid = threadIdx.x;
    const int b = blockIdx.x;
    const int wave = tid >> 6, lane = tid & 63;
    const int q = lane >> 4, l16 = lane & 15;    // quarter / lane-in-quarter
    const int m0 = b * 32;
    const int wm = wave & 1, wn = wave >> 1;     // 2 (M) x 4 (N) wave grid

    // ---- in-block counting sort of this tile's edges ----
    if (tid == 0) s_n = bcnt[b];
    if (tid < 256) cntL[tid] = 0;
    __syncthreads();
    const int n = s_n;
    const int* bd = bdata + b * CAP;
    for (int e = tid; e < n; e += 512) {
        const unsigned u = (unsigned)bd[e];
        const int key = ((u >> 19) & 31) * 8 + ((u >> 16) & 7);
        atomicAdd(&cntL[key], 1);
    }
    __syncthreads();
    if (tid < 256) segL[tid] = cntL[tid];
    __syncthreads();
    for (int off = 1; off < 256; off <<= 1) {
        int x = 0;
        if (tid < 256 && tid >= off) x = segL[tid - off];
        __syncthreads();
        if (tid < 256) segL[tid] += x;
        __syncthreads();
    }
    if (tid < 256) {
        const int ex = segL[tid] - cntL[tid];    // exclusive offset
        segL[tid] = ex;
        curL[tid] = ex;
    }
    __syncthreads();
    for (int e = tid; e < n; e += 512) {
        const unsigned u = (unsigned)bd[e];
        const int key = ((u >> 19) & 31) * 8 + ((u >> 16) & 7);
        const int pos = atomicAdd(&curL[key], 1);
        srcS[pos] = (unsigned short)(u & 0xffff);
    }
    __syncthreads();

    floatx4 acc[2];
#pragma unroll
    for (int nt = 0; nt < 2; ++nt) acc[nt] = (floatx4){0.f, 0.f, 0.f, 0.f};

    const unsigned short* fb = featB + 8 * l16;  // dims 8*l16 .. 8*l16+7

#pragma unroll
    for (int p = 0; p < 2; ++p) {
        // ---- agg phase: 4 nodes per wave, quarter q handles rel 4p+q ----
        for (int i = 0; i < 4; ++i) {
            const int nl = wave * 4 + i;         // local row 0..31
            const int key = nl * 8 + 4 * p + q;
            const int s0 = segL[key];
            const int len = cntL[key];
            float a0 = 0.f, a1 = 0.f, a2 = 0.f, a3 = 0.f;
            float a4 = 0.f, a5 = 0.f, a6 = 0.f, a7 = 0.f;
            for (int j = 0; j < len; j += 2) {   // 2 gathers in flight
                const int sa = srcS[s0 + j];
                const int jb = (j + 1 < len) ? (j + 1) : j;
                const int sb = srcS[s0 + jb];
                const bool pb = j + 1 < len;
                uint4 ua = *(const uint4*)&fb[sa * IN_DIM];
                uint4 ub = *(const uint4*)&fb[sb * IN_DIM];
                a0 += bflo(ua.x); a1 += bfhi(ua.x);
                a2 += bflo(ua.y); a3 += bfhi(ua.y);
                a4 += bflo(ua.z); a5 += bfhi(ua.z);
                a6 += bflo(ua.w); a7 += bfhi(ua.w);
                if (pb) {
                    a0 += bflo(ub.x); a1 += bfhi(ub.x);
                    a2 += bflo(ub.y); a3 += bfhi(ub.y);
                    a4 += bflo(ub.z); a5 += bfhi(ub.z);
                    a6 += bflo(ub.w); a7 += bfhi(ub.w);
                }
            }
            const float inv = (len > 0) ? 1.0f / (float)len : 0.0f;
            uintx4 pk;
            pk[0] = (unsigned)f2bf(a0 * inv) | ((unsigned)f2bf(a1 * inv) << 16);
            pk[1] = (unsigned)f2bf(a2 * inv) | ((unsigned)f2bf(a3 * inv) << 16);
            pk[2] = (unsigned)f2bf(a4 * inv) | ((unsigned)f2bf(a5 * inv) << 16);
            pk[3] = (unsigned)f2bf(a6 * inv) | ((unsigned)f2bf(a7 * inv) << 16);
            // unit u = q*16+l16 holds cols u*8..u*8+7; XOR-swizzle by row
            const int us = (q * 16 + l16) ^ (nl & 15);
            *(uintx4*)&Atile[(nl * 64 + us) * 8] = pk;
        }
        __syncthreads();                 // A-tile chunk visible

        // ---- GEMM phase: K-chunk p (512 cols), wave-tile 16x32 ----
        __builtin_amdgcn_s_setprio(1);
#pragma unroll
        for (int ksl = 0; ksl < 16; ++ksl) {
            const int ks = p * 16 + ksl;             // global k-slice
            const int r = wm * 16 + l16;
            const int us = (ksl * 4 + q) ^ (r & 15);
            bf16x8 a = *(const bf16x8*)&Atile[(r * 64 + us) * 8];
#pragma unroll
            for (int nt = 0; nt < 2; ++nt) {
                const int ntg = wn * 2 + nt;
                bf16x8 bb = *(const bf16x8*)&Wtf[(size_t)((ntg * 32 + ks) * 64 + lane) * 8];
                acc[nt] = __builtin_amdgcn_mfma_f32_16x16x32_bf16(a, bb, acc[nt], 0, 0, 0);
            }
        }
        __builtin_amdgcn_s_setprio(0);
        __syncthreads();                 // reads done before next pass writes
    }

    // ---- epilogue: acc -> LDS (D-layout scatter) -> full-line NT stores ----
    float* fbuf = (float*)Atile;     // 32 rows x 128 f32 = 16 KB
#pragma unroll
    for (int nt = 0; nt < 2; ++nt) {
        const int o = (wn * 2 + nt) * 16 + l16;
        const float bv = bias[o];
#pragma unroll
        for (int j = 0; j < 4; ++j) {
            const int r = wm * 16 + q * 4 + j;   // local row 0..31
            fbuf[r * 128 + o] = acc[nt][j] + bv;
        }
    }
    __syncthreads();
    {
        const int row = tid >> 4;            // 0..31
        const int col = (tid & 15) * 8;      // 0..120
        const int node = m0 + row;
        if (node < N_NODES) {
            floatx4 w0 = *(const floatx4*)&fbuf[row * 128 + col];
            floatx4 w1 = *(const floatx4*)&fbuf[row * 128 + col + 4];
            float* po = &out[(size_t)node * OUT_DIM + col];
            __builtin_nontemporal_store(w0, (floatx4*)po);
            __builtin_nontemporal_store(w1, (floatx4*)(po + 4));
        }
    }
}

extern "C" void kernel_launch(void* const* d_in, const int* in_sizes, int n_in,
                              void* d_out, int out_size, void* d_ws, size_t ws_size,
                              hipStream_t stream)
{
    const int*   tri      = (const int*)d_in[0];
    const float* features = (const float*)d_in[1];
    const float* W        = (const float*)d_in[2];
    const float* bias     = (const float*)d_in[3];
    float* out = (float*)d_out;

    char* ws = (char*)d_ws;
    unsigned short* Wtf = (unsigned short*)ws; ws += (size_t)OUT_DIM * KDIM * 2;  // 256 KB
    int* bcnt  = (int*)ws; ws += (size_t)2048 * 4;
    int* bdata = (int*)ws; ws += (size_t)NBKT * CAP * 4;                          // 12.8 MB
    unsigned short* featB = (unsigned short*)ws; ws += (size_t)N_NODES * IN_DIM * 2; // 12.8 MB
    (void)ws_size; (void)in_sizes; (void)n_in; (void)out_size;

    hipMemsetAsync(bcnt, 0, NBKT * sizeof(int), stream);
    prep2_kernel<<<EG_BLKS + CW_BLKS + FB_BLKS, 256, 0, stream>>>(
        tri, W, features, bcnt, bdata, Wtf, featB);
    fused_kernel<<<FUSE_BLKS, 512, 0, stream>>>(bcnt, bdata, featB, Wtf, bias, out);
}

// Round 13
// 226.771 us; speedup vs baseline: 2.1560x; 1.2551x over previous
//
#include <hip/hip_runtime.h>
#include <hip/hip_bf16.h>

#define N_NODES 50000
#define N_RELS 8
#define IN_DIM 128
#define OUT_DIM 128
#define N_EDGES 800000
#define KDIM (N_RELS * IN_DIM)             /* 1024 = GEMM K */
#define CAP 64                             /* entries per node bucket; Po(16) */
#define FUSE_BLKS 1563                     /* 1563 * 32 = 50016 >= N_NODES */
#define EG_BLKS ((N_EDGES / 4 + 255) / 256)    /* 782 edge-group blocks */
#define CW_BLKS ((N_RELS * IN_DIM * OUT_DIM + 255) / 256) /* 512 */
#define FB_BLKS ((N_NODES * IN_DIM / 8 + 255) / 256)      /* 3125 */

typedef __attribute__((ext_vector_type(8))) short bf16x8;
typedef __attribute__((ext_vector_type(4))) float floatx4;
typedef __attribute__((ext_vector_type(4))) unsigned int uintx4;

__device__ inline unsigned short f2bf(float f) {
    unsigned u = __builtin_bit_cast(unsigned, f);
    u += 0x7fff + ((u >> 16) & 1);   // round-to-nearest-even
    return (unsigned short)(u >> 16);
}
__device__ inline float bflo(unsigned u) {   // low bf16 of a packed pair
    return __builtin_bit_cast(float, u << 16);
}
__device__ inline float bfhi(unsigned u) {   // high bf16 of a packed pair
    return __builtin_bit_cast(float, u & 0xffff0000u);
}

// ---------------- prep2: per-node bucket-append + W/feature conversion -------
// R21: r12's append hit 1563 counters x ~512 atomics each -> same-address
// serialization made prep2 128 us at VALUBusy 0.7%. Bucket = tgt (50 K
// counters, ~16 hits each — r9-scatter contention level, which was fast).
// Entry = src | rel<<16; bdata[node*64 + pos]. Guard pos<CAP (P ~ 0).
__global__ void prep2_kernel(const int* __restrict__ tri, const float* __restrict__ W,
                             const float* __restrict__ features,
                             int* __restrict__ bcnt, int* __restrict__ bdata,
                             unsigned short* __restrict__ Wtf,
                             unsigned short* __restrict__ featB) {
    const int b = blockIdx.x;
    if (b < EG_BLKS) {
        int t = b * 256 + threadIdx.x;
        if (t >= N_EDGES / 4) return;
        const int4* tri4 = (const int4*)tri;
        int4 a = tri4[3 * t], v = tri4[3 * t + 1], c = tri4[3 * t + 2];
        // edges: (a.x,a.y,a.z) (a.w,v.x,v.y) (v.z,v.w,c.x) (c.y,c.z,c.w)
        int s[4] = { a.x, a.w, v.z, c.y };
        int r[4] = { a.y, v.x, v.w, c.z };
        int g[4] = { a.z, v.y, c.x, c.w };
#pragma unroll
        for (int k = 0; k < 4; ++k) {
            const int pos = atomicAdd(&bcnt[g[k]], 1);
            if (pos < CAP) bdata[g[k] * CAP + pos] = s[k] | (r[k] << 16);
        }
    } else if (b < EG_BLKS + CW_BLKS) {
        int idx = (b - EG_BLKS) * 256 + threadIdx.x;   // 0 .. 131071
        if (idx >= N_RELS * IN_DIM * OUT_DIM) return;
        int e  = idx & 7;
        int l  = (idx >> 3) & 63;
        int ks = (idx >> 9) & 31;
        int nt = idx >> 14;
        int o = nt * 16 + (l & 15);
        int k = ks * 32 + (l >> 4) * 8 + e;             // global K index
        Wtf[idx] = f2bf(W[(k >> 7) * (IN_DIM * OUT_DIM) + (k & 127) * OUT_DIM + o]);
    } else {
        int t = (b - EG_BLKS - CW_BLKS) * 256 + threadIdx.x;   // 8 floats each
        if (t >= N_NODES * IN_DIM / 8) return;
        const float4* f4 = (const float4*)features;
        float4 x = f4[2 * t], y = f4[2 * t + 1];
        uint4 o;
        o.x = (unsigned)f2bf(x.x) | ((unsigned)f2bf(x.y) << 16);
        o.y = (unsigned)f2bf(x.z) | ((unsigned)f2bf(x.w) << 16);
        o.z = (unsigned)f2bf(y.x) | ((unsigned)f2bf(y.y) << 16);
        o.w = (unsigned)f2bf(y.z) | ((unsigned)f2bf(y.w) << 16);
        ((uint4*)featB)[t] = o;
    }
}

// ---------------- fused: in-block LDS sort + agg + GEMM ----------------
// Load phase reads 32 per-node buckets (thread tid -> node tid>>4, entries
// strided by 16); hist/scan/scatter (key = nl*8+rel) and the gather/GEMM/
// epilogue are verbatim r12. LDS ~39 KB -> 4 blocks/CU.
__global__ __launch_bounds__(512, 8) void fused_kernel(
    const int* __restrict__ bcnt, const int* __restrict__ bdata,
    const unsigned short* __restrict__ featB,
    const unsigned short* __restrict__ Wtf,
    const float* __restrict__ bias,
    float* __restrict__ out)
{
    __shared__ __align__(16) unsigned short Atile[32 * 512]; // 32 KB
    __shared__ unsigned short srcS[2048];                    // 4 KB
    __shared__ int cntL[256];
    __shared__ int segL[256];
    __shared__ int curL[256];
    __shared__ int cntN[32];

    const int tid = threadIdx.x;
    const int b = blockIdx.x;
    const int wave = tid >> 6, lane = tid & 63;
    const int q = lane >> 4, l16 = lane & 15;    // quarter / lane-in-quarter
    const int m0 = b * 32;
    const int wm = wave & 1, wn = wave >> 1;     // 2 (M) x 4 (N) wave grid

    // ---- load + in-block counting sort of this tile's edges ----
    if (tid < 32) {
        const int node = m0 + tid;
        int c = (node < N_NODES) ? bcnt[node] : 0;
        cntN[tid] = (c > CAP) ? CAP : c;
    }
    if (tid < 256) cntL[tid] = 0;
    __syncthreads();
    {
        const int nl = tid >> 4;                 // node slot 0..31
        const int node = m0 + nl;
        const int cn = cntN[nl];
        for (int j = tid & 15; j < cn; j += 16) {
            const unsigned u = (unsigned)bdata[node * CAP + j];
            atomicAdd(&cntL[nl * 8 + ((u >> 16) & 7)], 1);
        }
    }
    __syncthreads();
    if (tid < 256) segL[tid] = cntL[tid];
    __syncthreads();
    for (int off = 1; off < 256; off <<= 1) {
        int x = 0;
        if (tid < 256 && tid >= off) x = segL[tid - off];
        __syncthreads();
        if (tid < 256) segL[tid] += x;
        __syncthreads();
    }
    if (tid < 256) {
        const int ex = segL[tid] - cntL[tid];    // exclusive offset
        segL[tid] = ex;
        curL[tid] = ex;
    }
    __syncthreads();
    {
        const int nl = tid >> 4;
        const int node = m0 + nl;
        const int cn = cntN[nl];
        for (int j = tid & 15; j < cn; j += 16) {
            const unsigned u = (unsigned)bdata[node * CAP + j];
            const int pos = atomicAdd(&curL[nl * 8 + ((u >> 16) & 7)], 1);
            srcS[pos] = (unsigned short)(u & 0xffff);
        }
    }
    __syncthreads();

    floatx4 acc[2];
#pragma unroll
    for (int nt = 0; nt < 2; ++nt) acc[nt] = (floatx4){0.f, 0.f, 0.f, 0.f};

    const unsigned short* fb = featB + 8 * l16;  // dims 8*l16 .. 8*l16+7

#pragma unroll
    for (int p = 0; p < 2; ++p) {
        // ---- agg phase: 4 nodes per wave, quarter q handles rel 4p+q ----
        for (int i = 0; i < 4; ++i) {
            const int nl = wave * 4 + i;         // local row 0..31
            const int key = nl * 8 + 4 * p + q;
            const int s0 = segL[key];
            const int len = cntL[key];
            float a0 = 0.f, a1 = 0.f, a2 = 0.f, a3 = 0.f;
            float a4 = 0.f, a5 = 0.f, a6 = 0.f, a7 = 0.f;
            for (int j = 0; j < len; j += 2) {   // 2 gathers in flight
                const int sa = srcS[s0 + j];
                const int jb = (j + 1 < len) ? (j + 1) : j;
                const int sb = srcS[s0 + jb];
                const bool pb = j + 1 < len;
                uint4 ua = *(const uint4*)&fb[sa * IN_DIM];
                uint4 ub = *(const uint4*)&fb[sb * IN_DIM];
                a0 += bflo(ua.x); a1 += bfhi(ua.x);
                a2 += bflo(ua.y); a3 += bfhi(ua.y);
                a4 += bflo(ua.z); a5 += bfhi(ua.z);
                a6 += bflo(ua.w); a7 += bfhi(ua.w);
                if (pb) {
                    a0 += bflo(ub.x); a1 += bfhi(ub.x);
                    a2 += bflo(ub.y); a3 += bfhi(ub.y);
                    a4 += bflo(ub.z); a5 += bfhi(ub.z);
                    a6 += bflo(ub.w); a7 += bfhi(ub.w);
                }
            }
            const float inv = (len > 0) ? 1.0f / (float)len : 0.0f;
            uintx4 pk;
            pk[0] = (unsigned)f2bf(a0 * inv) | ((unsigned)f2bf(a1 * inv) << 16);
            pk[1] = (unsigned)f2bf(a2 * inv) | ((unsigned)f2bf(a3 * inv) << 16);
            pk[2] = (unsigned)f2bf(a4 * inv) | ((unsigned)f2bf(a5 * inv) << 16);
            pk[3] = (unsigned)f2bf(a6 * inv) | ((unsigned)f2bf(a7 * inv) << 16);
            // unit u = q*16+l16 holds cols u*8..u*8+7; XOR-swizzle by row
            const int us = (q * 16 + l16) ^ (nl & 15);
            *(uintx4*)&Atile[(nl * 64 + us) * 8] = pk;
        }
        __syncthreads();                 // A-tile chunk visible

        // ---- GEMM phase: K-chunk p (512 cols), wave-tile 16x32 ----
        __builtin_amdgcn_s_setprio(1);
#pragma unroll
        for (int ksl = 0; ksl < 16; ++ksl) {
            const int ks = p * 16 + ksl;             // global k-slice
            const int r = wm * 16 + l16;
            const int us = (ksl * 4 + q) ^ (r & 15);
            bf16x8 a = *(const bf16x8*)&Atile[(r * 64 + us) * 8];
#pragma unroll
            for (int nt = 0; nt < 2; ++nt) {
                const int ntg = wn * 2 + nt;
                bf16x8 bb = *(const bf16x8*)&Wtf[(size_t)((ntg * 32 + ks) * 64 + lane) * 8];
                acc[nt] = __builtin_amdgcn_mfma_f32_16x16x32_bf16(a, bb, acc[nt], 0, 0, 0);
            }
        }
        __builtin_amdgcn_s_setprio(0);
        __syncthreads();                 // reads done before next pass writes
    }

    // ---- epilogue: acc -> LDS (D-layout scatter) -> full-line NT stores ----
    float* fbuf = (float*)Atile;     // 32 rows x 128 f32 = 16 KB
#pragma unroll
    for (int nt = 0; nt < 2; ++nt) {
        const int o = (wn * 2 + nt) * 16 + l16;
        const float bv = bias[o];
#pragma unroll
        for (int j = 0; j < 4; ++j) {
            const int r = wm * 16 + q * 4 + j;   // local row 0..31
            fbuf[r * 128 + o] = acc[nt][j] + bv;
        }
    }
    __syncthreads();
    {
        const int row = tid >> 4;            // 0..31
        const int col = (tid & 15) * 8;      // 0..120
        const int node = m0 + row;
        if (node < N_NODES) {
            floatx4 w0 = *(const floatx4*)&fbuf[row * 128 + col];
            floatx4 w1 = *(const floatx4*)&fbuf[row * 128 + col + 4];
            float* po = &out[(size_t)node * OUT_DIM + col];
            __builtin_nontemporal_store(w0, (floatx4*)po);
            __builtin_nontemporal_store(w1, (floatx4*)(po + 4));
        }
    }
}

extern "C" void kernel_launch(void* const* d_in, const int* in_sizes, int n_in,
                              void* d_out, int out_size, void* d_ws, size_t ws_size,
                              hipStream_t stream)
{
    const int*   tri      = (const int*)d_in[0];
    const float* features = (const float*)d_in[1];
    const float* W        = (const float*)d_in[2];
    const float* bias     = (const float*)d_in[3];
    float* out = (float*)d_out;

    char* ws = (char*)d_ws;
    unsigned short* Wtf = (unsigned short*)ws; ws += (size_t)OUT_DIM * KDIM * 2;  // 256 KB
    int* bcnt  = (int*)ws; ws += (size_t)50048 * 4;                               // 200 KB
    int* bdata = (int*)ws; ws += (size_t)N_NODES * CAP * 4;                       // 12.8 MB
    unsigned short* featB = (unsigned short*)ws; ws += (size_t)N_NODES * IN_DIM * 2; // 12.8 MB
    (void)ws_size; (void)in_sizes; (void)n_in; (void)out_size;

    hipMemsetAsync(bcnt, 0, 50048 * sizeof(int), stream);
    prep2_kernel<<<EG_BLKS + CW_BLKS + FB_BLKS, 256, 0, stream>>>(
        tri, W, features, bcnt, bdata, Wtf, featB);
    fused_kernel<<<FUSE_BLKS, 512, 0, stream>>>(bcnt, bdata, featB, Wtf, bias, out);
}